// Round 3
// baseline (1018.289 us; speedup 1.0000x reference)
//
#include <hip/hip_runtime.h>

#define N_USERS 100000
#define N_ITEMS 50000
#define N_NODES 150000
#define DIM 64
#define NNZ_C 2400000
#define BATCH 16384
#define NB 586          // ceil(150000/256) buckets of 256 rows
#define CAP 5120        // max edges/bucket (mean 4096, sigma 64; 16-sigma headroom)

// ---- Phase 1: bin edges into per-bucket slabs ----------------------------
__global__ void bucket_append(const int* __restrict__ rows, const int* __restrict__ cols,
                              const float* __restrict__ vals,
                              int* __restrict__ bcnt,
                              int2* __restrict__ bucket_cv,
                              unsigned char* __restrict__ bucket_rl) {
    int e = blockIdx.x * blockDim.x + threadIdx.x;
    if (e >= NNZ_C) return;
    int r = rows[e];
    int b = r >> 8;
    int pos = atomicAdd(&bcnt[b], 1);
    size_t s = (size_t)b * CAP + pos;
    int2 cv;
    cv.x = cols[e];
    cv.y = __float_as_int(vals[e]);
    bucket_cv[s] = cv;
    bucket_rl[s] = (unsigned char)(r & 255);
}

// ---- Exclusive scan of 586 bucket counts (single block) ------------------
__global__ void scan_buckets(const int* __restrict__ bcnt, int* __restrict__ bbase,
                             int* __restrict__ rowptr) {
    __shared__ int s[1024];
    int t = threadIdx.x;
    int v = (t < NB) ? bcnt[t] : 0;
    s[t] = v;
    __syncthreads();
    for (int off = 1; off < 1024; off <<= 1) {
        int u = (t >= off) ? s[t - off] : 0;
        __syncthreads();
        s[t] += u;
        __syncthreads();
    }
    if (t < NB) bbase[t] = s[t] - v;     // exclusive
    if (t == 0) rowptr[N_NODES] = NNZ_C;
}

// ---- Phase 2: one block per bucket -> rowptr + contiguous colval window --
__global__ void bucket_csr(const int* __restrict__ bcnt, const int* __restrict__ bbase,
                           const int2* __restrict__ bucket_cv,
                           const unsigned char* __restrict__ bucket_rl,
                           int* __restrict__ rowptr, int2* __restrict__ colval) {
    __shared__ int hist[256];
    __shared__ int scan[256];
    __shared__ int cur[256];
    int b = blockIdx.x;
    int tid = threadIdx.x;
    int cnt = bcnt[b];
    int base = bbase[b];
    hist[tid] = 0;
    __syncthreads();
    for (int i = tid; i < cnt; i += 256)
        atomicAdd(&hist[bucket_rl[(size_t)b * CAP + i]], 1);
    __syncthreads();
    int h = hist[tid];
    scan[tid] = h;
    __syncthreads();
    for (int off = 1; off < 256; off <<= 1) {
        int u = (tid >= off) ? scan[tid - off] : 0;
        __syncthreads();
        scan[tid] += u;
        __syncthreads();
    }
    int excl = scan[tid] - h;
    int g = b * 256 + tid;
    if (g < N_NODES) rowptr[g] = base + excl;
    cur[tid] = excl;
    __syncthreads();
    for (int i = tid; i < cnt; i += 256) {
        size_t s = (size_t)b * CAP + i;
        int rl = bucket_rl[s];
        int pos = atomicAdd(&cur[rl], 1);
        colval[base + pos] = bucket_cv[s];
    }
}

// ---- SpMM gather: one wave per row; 16 lanes x float4 per edge, 4 edges/iter
__global__ void spmm_gather4(const int* __restrict__ rowptr, const int2* __restrict__ colval,
                             const float* __restrict__ E, float* __restrict__ Eout) {
    int t = blockIdx.x * blockDim.x + threadIdx.x;
    int row = t >> 6;
    int lane = t & 63;
    if (row >= N_NODES) return;
    int ru = __builtin_amdgcn_readfirstlane(row);
    int start = rowptr[ru];
    int end = rowptr[ru + 1];
    int g = lane >> 4;      // edge slot within quad
    int q = lane & 15;      // float4 index within row
    float ax = 0.f, ay = 0.f, az = 0.f, aw = 0.f;
    for (int j = start; j < end; j += 4) {
        int jj = j + g;
        int2 cv = colval[jj];                       // padded past NNZ; masked below
        float v = (jj < end) ? __int_as_float(cv.y) : 0.f;
        int c = (jj < end) ? cv.x : 0;
        const float4* Erow = (const float4*)(E + (size_t)c * DIM);
        float4 x = Erow[q];
        ax += v * x.x; ay += v * x.y; az += v * x.z; aw += v * x.w;
    }
    // reduce across the 4 edge-groups (lanes ^16, ^32)
    ax += __shfl_xor(ax, 16, 64); ay += __shfl_xor(ay, 16, 64);
    az += __shfl_xor(az, 16, 64); aw += __shfl_xor(aw, 16, 64);
    ax += __shfl_xor(ax, 32, 64); ay += __shfl_xor(ay, 32, 64);
    az += __shfl_xor(az, 32, 64); aw += __shfl_xor(aw, 32, 64);
    if (g == 0) {
        float4 o; o.x = ax; o.y = ay; o.z = az; o.w = aw;
        ((float4*)(Eout + (size_t)row * DIM))[q] = o;
    }
}

// ---- accU[b] += E[U[b]], accI[b] += E[N_USERS + I[b]] --------------------
__global__ void batch_acc(const float* __restrict__ E, const int* __restrict__ U,
                          const int* __restrict__ I,
                          float* __restrict__ accU, float* __restrict__ accI) {
    int t = blockIdx.x * blockDim.x + threadIdx.x;
    int b = t >> 6;
    int lane = t & 63;
    if (b >= BATCH) return;
    int bu = __builtin_amdgcn_readfirstlane(b);
    int u = U[bu];
    int it = I[bu];
    accU[(size_t)b * DIM + lane] += E[(size_t)u * DIM + lane];
    accI[(size_t)b * DIM + lane] += E[(size_t)(N_USERS + it) * DIM + lane];
}

// ---- final dot, scale by 1/16 --------------------------------------------
__global__ void dot_out(const float* __restrict__ accU, const float* __restrict__ accI,
                        float* __restrict__ out) {
    int t = blockIdx.x * blockDim.x + threadIdx.x;
    int b = t >> 6;
    int lane = t & 63;
    if (b >= BATCH) return;
    float p = accU[(size_t)b * DIM + lane] * accI[(size_t)b * DIM + lane];
    #pragma unroll
    for (int off = 32; off; off >>= 1) p += __shfl_xor(p, off, 64);
    if (lane == 0) out[b] = p * (1.0f / 16.0f);
}

extern "C" void kernel_launch(void* const* d_in, const int* in_sizes, int n_in,
                              void* d_out, int out_size, void* d_ws, size_t ws_size,
                              hipStream_t stream) {
    const float* emb   = (const float*)d_in[0];
    const int*   Arows = (const int*)d_in[1];
    const int*   Acols = (const int*)d_in[2];
    const float* Avals = (const float*)d_in[3];
    const int*   U     = (const int*)d_in[4];
    const int*   I     = (const int*)d_in[5];
    float* out = (float*)d_out;

    char* ws = (char*)d_ws;
    size_t off = 0;
    auto alloc = [&](size_t bytes) {
        char* p = ws + off;
        off += (bytes + 255) & ~(size_t)255;
        return p;
    };
    float* e0     = (float*)alloc((size_t)N_NODES * DIM * 4);        // 38.4 MB
    char*  e1reg  =         alloc((size_t)N_NODES * DIM * 4);        // 38.4 MB (aliased w/ slabs)
    int2*  colval = (int2*) alloc(((size_t)NNZ_C + 8) * 8);          // 19.2 MB (+pad)
    float* accU   = (float*)alloc((size_t)BATCH * DIM * 4);
    float* accI   = (float*)alloc((size_t)BATCH * DIM * 4);
    int*   rowptr = (int*)  alloc((size_t)(N_NODES + 1) * 4);
    int*   bcnt   = (int*)  alloc((size_t)NB * 4);
    int*   bbase  = (int*)  alloc((size_t)NB * 4);

    // bucket slabs live inside e1's region (dead until layer-2 SpMM)
    float*         e1        = (float*)e1reg;
    int2*          bucket_cv = (int2*)e1reg;                          // 24.0 MB
    unsigned char* bucket_rl = (unsigned char*)(e1reg + (size_t)NB * CAP * 8); // 3.0 MB

    hipMemsetAsync(bcnt, 0, (size_t)NB * 4, stream);
    hipMemsetAsync(accU, 0, (size_t)BATCH * DIM * 4, stream);
    hipMemsetAsync(accI, 0, (size_t)BATCH * DIM * 4, stream);

    // CSR build (bucketed)
    bucket_append<<<(NNZ_C + 255) / 256, 256, 0, stream>>>(
        Arows, Acols, Avals, bcnt, bucket_cv, bucket_rl);
    scan_buckets<<<1, 1024, 0, stream>>>(bcnt, bbase, rowptr);
    bucket_csr<<<NB, 256, 0, stream>>>(bcnt, bbase, bucket_cv, bucket_rl, rowptr, colval);

    int spmm_blocks = (N_NODES * 64 + 255) / 256;
    int bacc_blocks = (BATCH * 64 + 255) / 256;

    // layer 0 (emb itself)
    batch_acc<<<bacc_blocks, 256, 0, stream>>>(emb, U, I, accU, accI);
    // layer 1: emb -> e0
    spmm_gather4<<<spmm_blocks, 256, 0, stream>>>(rowptr, colval, emb, e0);
    batch_acc<<<bacc_blocks, 256, 0, stream>>>(e0, U, I, accU, accI);
    // layer 2: e0 -> e1 (slabs are dead now)
    spmm_gather4<<<spmm_blocks, 256, 0, stream>>>(rowptr, colval, e0, e1);
    batch_acc<<<bacc_blocks, 256, 0, stream>>>(e1, U, I, accU, accI);
    // layer 3: e1 -> e0
    spmm_gather4<<<spmm_blocks, 256, 0, stream>>>(rowptr, colval, e1, e0);
    batch_acc<<<bacc_blocks, 256, 0, stream>>>(e0, U, I, accU, accI);

    dot_out<<<bacc_blocks, 256, 0, stream>>>(accU, accI, out);
}